// Round 16
// baseline (163.691 us; speedup 1.0000x reference)
//
#include <hip/hip_runtime.h>
#include <math.h>

// AtomQueryFieldNet: NQ=4096, NA=512, pair MLP 18->64->64->32->1, cutoff mask,
// per-query 3-vector reduction, 3->64->3 head.
//
// R16: RBF-pure K=16 chunk + rank-2 L1 C-init (on R14's zero-exchange chain).
//  - Repack permutes W1's K dim: RBF centers at k=0..15 -> L1 is ONE K=16 MFMA
//    per mt. Each lane computes exactly 4 exps, ZERO cndmask selects in X-build.
//  - bias/f0/f1 leave X: C-init = b1[row] + f0*W1[0,row] + f1*W1[1,row] via
//    per-lane f32 constants (b1v/w10v/w11v, fragment-ordered by repack).
//    f0,f1 now f32 (more accurate than old f16xf16 product).
//  - Chain (R14): mfma_16x16x16 C/D row = next-layer B-frag k; whole MLP in
//    registers, no LDS exchange (conflicts = 0). MFMAs/chunk: 64 -> 56.
//  - Structure (R12/R14): block=query, 4 waves, shared compacted list
//    (2-barrier prefix), 32-pair chunks round-robin. LDS ~8.5KB.
//  - fp16 in / fp32 accum; absmax <= 0.015625.

typedef _Float16 f16x4 __attribute__((ext_vector_type(4)));
typedef float    f32x4 __attribute__((ext_vector_type(4)));

#define CAP 352   // max in-range atoms/query (binomial mean 268, +7.4 sigma)
#define NT  2     // tiles (16 pairs) interleaved per chunk

// ---- repack: weights -> K=16 MFMA A-frag order + per-lane f32 constants ----
// frags (8B/lane): b 0..3 w1f[mt] (k=quad*4+j -> W1 row 2+k, RBF-permuted);
//   b 4..19 w2f[kc*4+mt]; b 20..27 w3f[kc*2+mt].
// f32 constants at +16KB (16B/lane), idx = quad*4+rr:
//   d 0..3 b1v; 4..7 w10v (W1 row0); 8..11 w11v (W1 row1); 12..15 b2v;
//   16..17 b3v; 18..19 w4v.
__global__ __launch_bounds__(64) void repack_kernel(
    const float* __restrict__ W1, const float* __restrict__ b1,
    const float* __restrict__ W2, const float* __restrict__ b2,
    const float* __restrict__ W3, const float* __restrict__ b3,
    const float* __restrict__ W4, char* __restrict__ ws)
{
    const int b = blockIdx.x, l = threadIdx.x;
    const int col = l & 15, quad = l >> 4;
    if (b < 28) {
        f16x4 v;
        #pragma unroll
        for (int j = 0; j < 4; ++j) {
            float x;
            if (b < 4) {
                const int mt = b;
                const int k = quad*4 + j;          // RBF center index
                x = W1[(2 + k)*64 + mt*16 + col];
            } else if (b < 20) {
                const int idx = b - 4, kc = idx >> 2, mt = idx & 3;
                const int k = kc*16 + quad*4 + j;
                x = W2[k*64 + mt*16 + col];
            } else {
                const int idx = b - 20, kc = idx >> 1, mt = idx & 1;
                const int k = kc*16 + quad*4 + j;
                x = W3[k*32 + mt*16 + col];
            }
            v[j] = (_Float16)x;
        }
        *(f16x4*)(ws + (b*64 + l)*8) = v;
    } else {
        const int d = b - 28;
        float o[4];
        #pragma unroll
        for (int rr = 0; rr < 4; ++rr) {
            const int idx = quad*4 + rr;
            if (d < 4)       o[rr] = b1[d*16 + idx];
            else if (d < 8)  o[rr] = W1[0*64 + (d-4)*16 + idx];
            else if (d < 12) o[rr] = W1[1*64 + (d-8)*16 + idx];
            else if (d < 16) o[rr] = b2[(d-12)*16 + idx];
            else if (d < 18) o[rr] = b3[(d-16)*16 + idx];
            else             o[rr] = W4[(d-18)*16 + idx];
        }
        *(float4*)(ws + 16384 + (d*64 + l)*16) = make_float4(o[0],o[1],o[2],o[3]);
    }
}

__device__ __forceinline__ f16x4 relu_cvt(f32x4 c) {
    return f16x4{(_Float16)fmaxf(c[0],0.f), (_Float16)fmaxf(c[1],0.f),
                 (_Float16)fmaxf(c[2],0.f), (_Float16)fmaxf(c[3],0.f)};
}

__global__ __launch_bounds__(256, 1) void aqfn_kernel(
    const float* __restrict__ atom_pos,   // (512,3)
    const float* __restrict__ atom_feat,  // (512,2)
    const float* __restrict__ query_pos,  // (4096,3)
    const float* __restrict__ b4,         // (1)
    const float* __restrict__ W5, const float* __restrict__ b5,  // (3,64),(64)
    const float* __restrict__ W6, const float* __restrict__ b6,  // (64,3),(3)
    const char*  __restrict__ ws,         // repacked weights
    float* __restrict__ out)              // (4096,3)
{
    __shared__ __align__(16) float4 rbuf[CAP];   // (rx,ry,rz,dist)
    __shared__ __align__(16) float2 fbuf[CAP];   // (f0,f1) f32
    __shared__ float wred[4][3];
    __shared__ int   wcnt[4];

    const int tid  = threadIdx.x;
    const int wave = __builtin_amdgcn_readfirstlane(tid >> 6);
    const int lane = tid & 63;
    const int col  = lane & 15;
    const int quad = lane >> 4;
    const int q    = blockIdx.x;

    // ---- fragment + constant preload (coalesced) ----
    const f16x4*  wsf = (const f16x4*)ws;
    const float4* wsb = (const float4*)(ws + 16384);
    f16x4 w1f[4], w2f[4][4], w3f[4][2];
    #pragma unroll
    for (int mt = 0; mt < 4; ++mt) w1f[mt] = wsf[mt*64 + lane];
    #pragma unroll
    for (int kc = 0; kc < 4; ++kc)
        #pragma unroll
        for (int mt = 0; mt < 4; ++mt) w2f[kc][mt] = wsf[(4 + kc*4 + mt)*64 + lane];
    #pragma unroll
    for (int kc = 0; kc < 4; ++kc)
        #pragma unroll
        for (int mt = 0; mt < 2; ++mt) w3f[kc][mt] = wsf[(20 + kc*2 + mt)*64 + lane];
    float4 b1v[4], w10v[4], w11v[4], b2v[4], b3v[2], w4v[2];
    #pragma unroll
    for (int mt = 0; mt < 4; ++mt) {
        b1v[mt]  = wsb[(0  + mt)*64 + lane];
        w10v[mt] = wsb[(4  + mt)*64 + lane];
        w11v[mt] = wsb[(8  + mt)*64 + lane];
        b2v[mt]  = wsb[(12 + mt)*64 + lane];
    }
    #pragma unroll
    for (int mt = 0; mt < 2; ++mt) { b3v[mt] = wsb[(16+mt)*64 + lane];
                                     w4v[mt] = wsb[(18+mt)*64 + lane]; }
    const float b4v = b4[0];

    // per-lane RBF centers for k = quad*4 + j
    float cj[4];
    #pragma unroll
    for (int j = 0; j < 4; ++j) cj[j] = 0.4f * (float)(quad*4 + j);

    const float qx = query_pos[q*3+0];
    const float qy = query_pos[q*3+1];
    const float qz = query_pos[q*3+2];

    // ---- pass 1: per-wave ballots over segment [wave*128, +128) ----
    float rxv[2], ryv[2], rzv[2], dv[2], f0v[2], f1v[2];
    unsigned long long msk[2];
    int mycnt = 0;
    #pragma unroll
    for (int it = 0; it < 2; ++it) {
        const int a = wave*128 + it*64 + lane;
        const float rx = qx - atom_pos[a*3+0];
        const float ry = qy - atom_pos[a*3+1];
        const float rz = qz - atom_pos[a*3+2];
        const float ex = __fadd_rn(rx, 1e-12f);
        const float ey = __fadd_rn(ry, 1e-12f);
        const float ez = __fadd_rn(rz, 1e-12f);
        const float dd = __fadd_rn(__fadd_rn(__fmul_rn(ex,ex), __fmul_rn(ey,ey)),
                                   __fmul_rn(ez,ez));
        const float dist = sqrtf(dd);
        rxv[it] = rx; ryv[it] = ry; rzv[it] = rz; dv[it] = dist;
        f0v[it] = atom_feat[a*2+0]; f1v[it] = atom_feat[a*2+1];
        msk[it] = __ballot(dist <= 6.0f);
        mycnt  += (int)__popcll(msk[it]);
    }
    if (lane == 0) wcnt[wave] = mycnt;
    __syncthreads();

    int base = 0, count = 0;
    #pragma unroll
    for (int w = 0; w < 4; ++w) {
        const int c = wcnt[w];
        if (w < wave) base += c;
        count += c;
    }
    if (count > CAP) count = CAP;

    // ---- pass 2: prefix-offset writes into the shared list ----
    {
        int off0 = base;
        #pragma unroll
        for (int it = 0; it < 2; ++it) {
            const bool in = (msk[it] >> lane) & 1ull;
            const int  p  = off0 + (int)__popcll(msk[it] & ((1ull << lane) - 1ull));
            if (in && p < CAP) {
                rbuf[p] = make_float4(rxv[it], ryv[it], rzv[it], dv[it]);
                fbuf[p] = make_float2(f0v[it], f1v[it]);
            }
            off0 += (int)__popcll(msk[it]);
        }
    }
    __syncthreads();

    // ---- MLP over shared list: 32-pair chunks round-robin, all in-register ----
    float wacc0 = 0.f, wacc1 = 0.f, wacc2 = 0.f;
    const int nchunks = (count + (NT*16 - 1)) / (NT*16);

    #pragma unroll 1
    for (int chunk = wave; chunk < nchunks; chunk += 4) {
        const int row0 = chunk * (NT*16);

        float4 rv[NT]; float2 ffv[NT];
        #pragma unroll
        for (int u = 0; u < NT; ++u) {
            int pr = row0 + u*16 + col;
            if (pr >= count) pr = count - 1;
            rv[u]  = rbuf[pr];
            ffv[u] = fbuf[pr];
        }

        // X RBF B-frags (pure): xa[u][j], k = quad*4+j, value exp(-10(d-0.4k)^2)
        f16x4 xa[NT];
        #pragma unroll
        for (int u = 0; u < NT; ++u) {
            const float dist = rv[u].w;
            #pragma unroll
            for (int j = 0; j < 4; ++j) {
                const float tt = dist - cj[j];
                xa[u][j] = (_Float16)__expf(-10.0f * tt * tt);
            }
        }

        // ---- L1: rank-2 C-init + ONE K=16 MFMA per mt ----
        f16x4 a2[NT][4];
        #pragma unroll
        for (int u = 0; u < NT; ++u) {
            const float f0 = ffv[u].x, f1 = ffv[u].y;
            #pragma unroll
            for (int mt = 0; mt < 4; ++mt) {
                f32x4 c;
                const float* bb = &b1v[mt].x;
                const float* wa = &w10v[mt].x;
                const float* wb = &w11v[mt].x;
                #pragma unroll
                for (int rr = 0; rr < 4; ++rr)
                    c[rr] = fmaf(f0, wa[rr], fmaf(f1, wb[rr], bb[rr]));
                c = __builtin_amdgcn_mfma_f32_16x16x16f16(w1f[mt], xa[u], c, 0, 0, 0);
                a2[u][mt] = relu_cvt(c);
            }
        }

        // ---- L2: output rows == next B-frag k-chunks ----
        f16x4 a3[NT][4];
        #pragma unroll
        for (int u = 0; u < NT; ++u)
            #pragma unroll
            for (int mt = 0; mt < 4; ++mt) {
                f32x4 c = {b2v[mt].x, b2v[mt].y, b2v[mt].z, b2v[mt].w};
                #pragma unroll
                for (int kc = 0; kc < 4; ++kc)
                    c = __builtin_amdgcn_mfma_f32_16x16x16f16(w2f[kc][mt], a2[u][kc], c, 0, 0, 0);
                a3[u][mt] = relu_cvt(c);
            }

        // ---- L3 + L4 partial + quad-reduce + fused accumulation ----
        #pragma unroll
        for (int u = 0; u < NT; ++u) {
            float s = 0.f;
            #pragma unroll
            for (int mt = 0; mt < 2; ++mt) {
                f32x4 c = {b3v[mt].x, b3v[mt].y, b3v[mt].z, b3v[mt].w};
                #pragma unroll
                for (int kc = 0; kc < 4; ++kc)
                    c = __builtin_amdgcn_mfma_f32_16x16x16f16(w3f[kc][mt], a3[u][kc], c, 0, 0, 0);
                const float* wv = &w4v[mt].x;
                #pragma unroll
                for (int rr = 0; rr < 4; ++rr)
                    s = fmaf(fmaxf(c[rr], 0.f), wv[rr], s);
            }
            s += __shfl_xor(s, 16);
            s += __shfl_xor(s, 32);
            s += b4v;
            const int  p2  = row0 + u*16 + col;
            const bool vld = (p2 < count);
            const float inv = __builtin_amdgcn_rcpf(rv[u].w + 1e-12f);
            const float wm  = vld ? (s * inv) : 0.f;
            wacc0 = fmaf(wm, rv[u].x, wacc0);
            wacc1 = fmaf(wm, rv[u].y, wacc1);
            wacc2 = fmaf(wm, rv[u].z, wacc2);
        }
    }

    // ---- 64-lane butterfly; each pair counted by 4 quads -> x0.25 ----
    #pragma unroll
    for (int off = 1; off < 64; off <<= 1) {
        wacc0 += __shfl_xor(wacc0, off);
        wacc1 += __shfl_xor(wacc1, off);
        wacc2 += __shfl_xor(wacc2, off);
    }
    if (lane == 0) {
        wred[wave][0] = wacc0 * 0.25f;
        wred[wave][1] = wacc1 * 0.25f;
        wred[wave][2] = wacc2 * 0.25f;
    }
    __syncthreads();

    // ---- head: 3 -> 64 -> 3 (wave 0, lane = hidden unit) ----
    if (wave == 0) {
        const float v0 = wred[0][0] + wred[1][0] + wred[2][0] + wred[3][0];
        const float v1 = wred[0][1] + wred[1][1] + wred[2][1] + wred[3][1];
        const float v2 = wred[0][2] + wred[1][2] + wred[2][2] + wred[3][2];
        float th = fmaf(v0, W5[lane],
                   fmaf(v1, W5[64+lane],
                   fmaf(v2, W5[128+lane], b5[lane])));
        th = fmaxf(th, 0.f);
        float o0 = th * W6[lane*3+0];
        float o1 = th * W6[lane*3+1];
        float o2 = th * W6[lane*3+2];
        #pragma unroll
        for (int off = 1; off < 64; off <<= 1) {
            o0 += __shfl_xor(o0, off);
            o1 += __shfl_xor(o1, off);
            o2 += __shfl_xor(o2, off);
        }
        if (lane == 0) {
            out[q*3+0] = o0 + b6[0];
            out[q*3+1] = o1 + b6[1];
            out[q*3+2] = o2 + b6[2];
        }
    }
}

extern "C" void kernel_launch(void* const* d_in, const int* in_sizes, int n_in,
                              void* d_out, int out_size, void* d_ws, size_t ws_size,
                              hipStream_t stream) {
    const float* atom_pos  = (const float*)d_in[0];
    const float* atom_feat = (const float*)d_in[1];
    const float* query_pos = (const float*)d_in[2];
    const float* W1 = (const float*)d_in[3];  const float* b1 = (const float*)d_in[4];
    const float* W2 = (const float*)d_in[5];  const float* b2 = (const float*)d_in[6];
    const float* W3 = (const float*)d_in[7];  const float* b3 = (const float*)d_in[8];
    const float* W4 = (const float*)d_in[9];  const float* b4 = (const float*)d_in[10];
    const float* W5 = (const float*)d_in[11]; const float* b5 = (const float*)d_in[12];
    const float* W6 = (const float*)d_in[13]; const float* b6 = (const float*)d_in[14];
    float* out = (float*)d_out;
    char*  ws  = (char*)d_ws;   // 14KB frags + 20KB f32 constants

    hipLaunchKernelGGL(repack_kernel, dim3(48), dim3(64), 0, stream,
                       W1, b1, W2, b2, W3, b3, W4, ws);
    hipLaunchKernelGGL(aqfn_kernel, dim3(4096), dim3(256), 0, stream,
                       atom_pos, atom_feat, query_pos, b4, W5, b5, W6, b6,
                       (const char*)ws, out);
}

// Round 17
// 118.328 us; speedup vs baseline: 1.3834x; 1.3834x over previous
//
#include <hip/hip_runtime.h>
#include <math.h>

// AtomQueryFieldNet: NQ=4096, NA=512, pair MLP 18->64->64->32->1, cutoff mask,
// per-query 3-vector reduction, 3->64->3 head.
//
// R17: R12 (champion, 41.2us) + permuted-W1 X-build (fewer selects).
//  - R13..R16 all lost to R12: 8-wave blocks (LDS->occ cliff), K=16 chain
//    (K=16 MFMA costs ~= K=32 cycles -> wastes matrix pipe), f32 const arrays
//    (VGPR 136 -> occ 9%). Structure locked to R12.
//  - Only change: repack orders W1aug K as [rbf(16) | b1 | f0row | f1row | 0..]
//    so X-build is: quads 0-1 pure exps (no selects), quad 2 compile-time
//    specials (1.0/f0/f1 at j=0,1,2), quad 3 zero. ~4 selects/j -> ~1.
//  - Hot loop otherwise byte-identical to R12: block=query, 4 waves, shared
//    compacted list (2-barrier prefix), 32-pair chunks round-robin, NT=2,
//    transposed K=32 MFMA + per-wave LDS exchange, fused L4+accumulation.
//  - fp16 in / fp32 accum; absmax 0.015625.

typedef _Float16 f16x8 __attribute__((ext_vector_type(8)));
typedef _Float16 f16x4 __attribute__((ext_vector_type(4)));
typedef _Float16 f16x2 __attribute__((ext_vector_type(2)));
typedef float    f32x4 __attribute__((ext_vector_type(4)));

#define CAP 352   // max in-range atoms/query (geometric max ~270)
#define XP2 72    // exchange row pitch in f16 (144B rows; b64/b128 aligned)
#define NT  2     // tiles (16 pairs) interleaved per chunk

// ---- repack: weights -> MFMA fragment order in d_ws ----
// W1aug K-permutation: k 0..15 = RBF centers (W1 rows 2..17), k16 = b1,
// k17 = W1 row 0 (f0), k18 = W1 row 1 (f1), k19.. = 0.
__global__ __launch_bounds__(64) void repack_kernel(
    const float* __restrict__ W1, const float* __restrict__ b1,
    const float* __restrict__ W2, const float* __restrict__ b2,
    const float* __restrict__ W3, const float* __restrict__ b3,
    const float* __restrict__ W4, char* __restrict__ ws)
{
    const int b = blockIdx.x, l = threadIdx.x;
    const int col = l & 15, quad = l >> 4;
    if (b < 16) {
        f16x8 v;
        #pragma unroll
        for (int j = 0; j < 8; ++j) {
            const int k = quad*8 + j;
            float x;
            if (b < 4) {
                const int mt = b;
                if (k < 16)       x = W1[(2 + k)*64 + mt*16 + col];  // RBF center k
                else if (k == 16) x = b1[mt*16 + col];
                else if (k == 17) x = W1[0*64 + mt*16 + col];        // f0 row
                else if (k == 18) x = W1[1*64 + mt*16 + col];        // f1 row
                else              x = 0.0f;
            } else if (b < 12) {
                const int kc = (b-4) >> 2, mt = (b-4) & 3;
                x = W2[(kc*32 + k)*64 + mt*16 + col];
            } else {
                const int kc = (b-12) >> 1, mt = (b-12) & 1;
                x = W3[(kc*32 + k)*32 + mt*16 + col];
            }
            v[j] = (_Float16)x;
        }
        *(f16x8*)(ws + (b*64 + l)*16) = v;
    } else {
        const int d = b - 16;
        float o[4];
        #pragma unroll
        for (int rr = 0; rr < 4; ++rr) {
            const int idx = quad*4 + rr;
            if (d < 4)      o[rr] = b2[d*16 + idx];
            else if (d < 6) o[rr] = b3[(d-4)*16 + idx];
            else            o[rr] = W4[(d-6)*16 + idx];
        }
        *(float4*)(ws + 16384 + (d*64 + l)*16) = make_float4(o[0],o[1],o[2],o[3]);
    }
}

__global__ __launch_bounds__(256, 1) void aqfn_kernel(
    const float* __restrict__ atom_pos,   // (512,3)
    const float* __restrict__ atom_feat,  // (512,2)
    const float* __restrict__ query_pos,  // (4096,3)
    const float* __restrict__ b4,         // (1)
    const float* __restrict__ W5, const float* __restrict__ b5,  // (3,64),(64)
    const float* __restrict__ W6, const float* __restrict__ b6,  // (64,3),(3)
    const char*  __restrict__ ws,         // repacked weights
    float* __restrict__ out)              // (4096,3)
{
    __shared__ __align__(16) float4   rbuf[CAP];            // shared compacted list
    __shared__ __align__(16) f16x2    fbuf[CAP];
    __shared__ __align__(16) _Float16 exch[4][NT][16*XP2];  // per-wave exchange
    __shared__ float wred[4][3];
    __shared__ int   wcnt[4];

    const int tid  = threadIdx.x;
    const int wave = __builtin_amdgcn_readfirstlane(tid >> 6);
    const int lane = tid & 63;
    const int col  = lane & 15;
    const int quad = lane >> 4;
    const int q    = blockIdx.x;

    // ---- fragment preload: 24 coalesced dwordx4 loads (per wave) ----
    const f16x8*  wsf = (const f16x8*)ws;
    const float4* wsb = (const float4*)(ws + 16384);
    f16x8 w1f[4], w2f[2][4], w3f[2][2];
    #pragma unroll
    for (int mt = 0; mt < 4; ++mt) w1f[mt] = wsf[mt*64 + lane];
    #pragma unroll
    for (int kc = 0; kc < 2; ++kc)
        #pragma unroll
        for (int mt = 0; mt < 4; ++mt) w2f[kc][mt] = wsf[(4 + kc*4 + mt)*64 + lane];
    #pragma unroll
    for (int kc = 0; kc < 2; ++kc)
        #pragma unroll
        for (int mt = 0; mt < 2; ++mt) w3f[kc][mt] = wsf[(12 + kc*2 + mt)*64 + lane];
    float4 b2v[4], b3v[2], w4v[2];
    #pragma unroll
    for (int mt = 0; mt < 4; ++mt) b2v[mt] = wsb[mt*64 + lane];
    #pragma unroll
    for (int mt = 0; mt < 2; ++mt) { b3v[mt] = wsb[(4+mt)*64 + lane];
                                     w4v[mt] = wsb[(6+mt)*64 + lane]; }
    const float b4v = b4[0];

    const float qx = query_pos[q*3+0];
    const float qy = query_pos[q*3+1];
    const float qz = query_pos[q*3+2];

    // per-lane RBF center base for k = quad*8 + j (valid k<16; others discarded)
    const float cbase = 0.4f * (float)(quad*8);
    const bool  lowq  = (quad < 2);
    const bool  isq2  = (quad == 2);

    // ---- pass 1: per-wave ballots over segment [wave*128, +128), keep data ----
    float rxv[2], ryv[2], rzv[2], dv[2], f0v[2], f1v[2];
    unsigned long long msk[2];
    int mycnt = 0;
    #pragma unroll
    for (int it = 0; it < 2; ++it) {
        const int a = wave*128 + it*64 + lane;
        const float rx = qx - atom_pos[a*3+0];
        const float ry = qy - atom_pos[a*3+1];
        const float rz = qz - atom_pos[a*3+2];
        const float ex = __fadd_rn(rx, 1e-12f);
        const float ey = __fadd_rn(ry, 1e-12f);
        const float ez = __fadd_rn(rz, 1e-12f);
        const float dd = __fadd_rn(__fadd_rn(__fmul_rn(ex,ex), __fmul_rn(ey,ey)),
                                   __fmul_rn(ez,ez));
        const float dist = sqrtf(dd);
        rxv[it] = rx; ryv[it] = ry; rzv[it] = rz; dv[it] = dist;
        f0v[it] = atom_feat[a*2+0]; f1v[it] = atom_feat[a*2+1];
        msk[it] = __ballot(dist <= 6.0f);
        mycnt  += (int)__popcll(msk[it]);
    }
    if (lane == 0) wcnt[wave] = mycnt;
    __syncthreads();

    // exclusive prefix over 4 wave counts
    int base = 0, count = 0;
    #pragma unroll
    for (int w = 0; w < 4; ++w) {
        const int c = wcnt[w];
        if (w < wave) base += c;
        count += c;
    }
    if (count > CAP) count = CAP;

    // ---- pass 2: prefix-offset writes into the shared list ----
    {
        int off0 = base;
        #pragma unroll
        for (int it = 0; it < 2; ++it) {
            const bool in = (msk[it] >> lane) & 1ull;
            const int  p  = off0 + (int)__popcll(msk[it] & ((1ull << lane) - 1ull));
            if (in && p < CAP) {
                rbuf[p] = make_float4(rxv[it], ryv[it], rzv[it], dv[it]);
                fbuf[p] = f16x2{(_Float16)f0v[it], (_Float16)f1v[it]};
            }
            off0 += (int)__popcll(msk[it]);
        }
    }
    __syncthreads();

    // ---- MLP over shared list: 32-pair chunks round-robin across waves ----
    float wacc0 = 0.f, wacc1 = 0.f, wacc2 = 0.f;
    const int nchunks = (count + (NT*16 - 1)) / (NT*16);

    #pragma unroll 1
    for (int chunk = wave; chunk < nchunks; chunk += 4) {
        const int row0 = chunk * (NT*16);

        float4 rv[NT]; f16x2 ffv[NT];
        #pragma unroll
        for (int u = 0; u < NT; ++u) {
            int pr = row0 + u*16 + col;
            if (pr >= count) pr = count - 1;
            rv[u]  = rbuf[pr];
            ffv[u] = fbuf[pr];
        }

        // X B-frags (permuted W1aug): x = [rbf(16) | 1 | f0 | f1 | 0...]
        // quads 0-1: pure exps. quad 2: specials at j=0,1,2. quad 3: zero.
        f16x8 xa[NT];
        #pragma unroll
        for (int u = 0; u < NT; ++u) {
            const float dist = rv[u].w;
            const _Float16 f0h = ffv[u][0], f1h = ffv[u][1];
            const _Float16 z   = (_Float16)0.0f;
            #pragma unroll
            for (int j = 0; j < 8; ++j) {
                const float tt = dist - (cbase + 0.4f * (float)j);
                const _Float16 e = (_Float16)__expf(-10.0f * tt * tt);
                _Float16 sp;                     // quad-2 special, compile-time j
                if      (j == 0) sp = isq2 ? (_Float16)1.0f : z;
                else if (j == 1) sp = isq2 ? f0h : z;
                else if (j == 2) sp = isq2 ? f1h : z;
                else             sp = z;
                xa[u][j] = lowq ? e : sp;
            }
        }

        // ---- L1 transposed: h1^T[mt*16+quad*4+rr][pair=col] ----
        #pragma unroll
        for (int u = 0; u < NT; ++u)
            #pragma unroll
            for (int mt = 0; mt < 4; ++mt) {
                f32x4 c = {0.f, 0.f, 0.f, 0.f};
                c = __builtin_amdgcn_mfma_f32_16x16x32_f16(w1f[mt], xa[u], c, 0, 0, 0);
                f16x4 pk = {(_Float16)fmaxf(c[0],0.f), (_Float16)fmaxf(c[1],0.f),
                            (_Float16)fmaxf(c[2],0.f), (_Float16)fmaxf(c[3],0.f)};
                *(f16x4*)&exch[wave][u][col*XP2 + mt*16 + quad*4] = pk;
            }
        f16x8 a2[NT][2];
        #pragma unroll
        for (int u = 0; u < NT; ++u)
            #pragma unroll
            for (int kc = 0; kc < 2; ++kc)
                a2[u][kc] = *(const f16x8*)&exch[wave][u][col*XP2 + kc*32 + quad*8];

        // ---- L2 transposed ----
        #pragma unroll
        for (int u = 0; u < NT; ++u)
            #pragma unroll
            for (int mt = 0; mt < 4; ++mt) {
                f32x4 c = {b2v[mt].x, b2v[mt].y, b2v[mt].z, b2v[mt].w};
                c = __builtin_amdgcn_mfma_f32_16x16x32_f16(w2f[0][mt], a2[u][0], c, 0, 0, 0);
                c = __builtin_amdgcn_mfma_f32_16x16x32_f16(w2f[1][mt], a2[u][1], c, 0, 0, 0);
                f16x4 pk = {(_Float16)fmaxf(c[0],0.f), (_Float16)fmaxf(c[1],0.f),
                            (_Float16)fmaxf(c[2],0.f), (_Float16)fmaxf(c[3],0.f)};
                *(f16x4*)&exch[wave][u][col*XP2 + mt*16 + quad*4] = pk;
            }
        f16x8 a3[NT][2];
        #pragma unroll
        for (int u = 0; u < NT; ++u)
            #pragma unroll
            for (int kc = 0; kc < 2; ++kc)
                a3[u][kc] = *(const f16x8*)&exch[wave][u][col*XP2 + kc*32 + quad*8];

        // ---- L3 transposed + L4 partial + quad-reduce + fused accumulation ----
        #pragma unroll
        for (int u = 0; u < NT; ++u) {
            float s = 0.f;
            #pragma unroll
            for (int mt = 0; mt < 2; ++mt) {
                f32x4 c = {b3v[mt].x, b3v[mt].y, b3v[mt].z, b3v[mt].w};
                c = __builtin_amdgcn_mfma_f32_16x16x32_f16(w3f[0][mt], a3[u][0], c, 0, 0, 0);
                c = __builtin_amdgcn_mfma_f32_16x16x32_f16(w3f[1][mt], a3[u][1], c, 0, 0, 0);
                const float* wv = &w4v[mt].x;
                #pragma unroll
                for (int rr = 0; rr < 4; ++rr)
                    s = fmaf(fmaxf(c[rr], 0.f), wv[rr], s);
            }
            s += __shfl_xor(s, 16);
            s += __shfl_xor(s, 32);
            s += b4v;
            const int  p2  = row0 + u*16 + col;
            const bool vld = (p2 < count);
            const float inv = __builtin_amdgcn_rcpf(rv[u].w + 1e-12f);
            const float wm  = vld ? (s * inv) : 0.f;
            wacc0 = fmaf(wm, rv[u].x, wacc0);
            wacc1 = fmaf(wm, rv[u].y, wacc1);
            wacc2 = fmaf(wm, rv[u].z, wacc2);
        }
    }

    // ---- 64-lane butterfly; each pair counted by 4 quads -> x0.25 ----
    #pragma unroll
    for (int off = 1; off < 64; off <<= 1) {
        wacc0 += __shfl_xor(wacc0, off);
        wacc1 += __shfl_xor(wacc1, off);
        wacc2 += __shfl_xor(wacc2, off);
    }
    if (lane == 0) {
        wred[wave][0] = wacc0 * 0.25f;
        wred[wave][1] = wacc1 * 0.25f;
        wred[wave][2] = wacc2 * 0.25f;
    }
    __syncthreads();

    // ---- head: 3 -> 64 -> 3 (wave 0, lane = hidden unit) ----
    if (wave == 0) {
        const float v0 = wred[0][0] + wred[1][0] + wred[2][0] + wred[3][0];
        const float v1 = wred[0][1] + wred[1][1] + wred[2][1] + wred[3][1];
        const float v2 = wred[0][2] + wred[1][2] + wred[2][2] + wred[3][2];
        float th = fmaf(v0, W5[lane],
                   fmaf(v1, W5[64+lane],
                   fmaf(v2, W5[128+lane], b5[lane])));
        th = fmaxf(th, 0.f);
        float o0 = th * W6[lane*3+0];
        float o1 = th * W6[lane*3+1];
        float o2 = th * W6[lane*3+2];
        #pragma unroll
        for (int off = 1; off < 64; off <<= 1) {
            o0 += __shfl_xor(o0, off);
            o1 += __shfl_xor(o1, off);
            o2 += __shfl_xor(o2, off);
        }
        if (lane == 0) {
            out[q*3+0] = o0 + b6[0];
            out[q*3+1] = o1 + b6[1];
            out[q*3+2] = o2 + b6[2];
        }
    }
}

extern "C" void kernel_launch(void* const* d_in, const int* in_sizes, int n_in,
                              void* d_out, int out_size, void* d_ws, size_t ws_size,
                              hipStream_t stream) {
    const float* atom_pos  = (const float*)d_in[0];
    const float* atom_feat = (const float*)d_in[1];
    const float* query_pos = (const float*)d_in[2];
    const float* W1 = (const float*)d_in[3];  const float* b1 = (const float*)d_in[4];
    const float* W2 = (const float*)d_in[5];  const float* b2 = (const float*)d_in[6];
    const float* W3 = (const float*)d_in[7];  const float* b3 = (const float*)d_in[8];
    const float* W4 = (const float*)d_in[9];  const float* b4 = (const float*)d_in[10];
    const float* W5 = (const float*)d_in[11]; const float* b5 = (const float*)d_in[12];
    const float* W6 = (const float*)d_in[13]; const float* b6 = (const float*)d_in[14];
    float* out = (float*)d_out;
    char*  ws  = (char*)d_ws;   // 16KB frags + 8KB biases

    hipLaunchKernelGGL(repack_kernel, dim3(24), dim3(64), 0, stream,
                       W1, b1, W2, b2, W3, b3, W4, ws);
    hipLaunchKernelGGL(aqfn_kernel, dim3(4096), dim3(256), 0, stream,
                       atom_pos, atom_feat, query_pos, b4, W5, b5, W6, b6,
                       (const char*)ws, out);
}

// Round 18
// 118.067 us; speedup vs baseline: 1.3864x; 1.0022x over previous
//
#include <hip/hip_runtime.h>
#include <math.h>

// AtomQueryFieldNet: NQ=4096, NA=512, pair MLP 18->64->64->32->1, cutoff mask,
// per-query 3-vector reduction, 3->64->3 head.
//
// R18: R17 champion + 2 queries/block pooled chunks (grid 2048 x 256).
//  - Plateau diagnosis: chain-latency x ~7 waves/CU residency. Remaining
//    positive-arithmetic term: chunk quantization. 1 query = 6 chunks over
//    4 waves -> makespan 2 (waves idle 25-33%). 2 queries pooled = ~12 chunks
//    -> 3 each, makespan 1.5 chunks/query-equiv. Preload amortized 2x.
//  - Waves 0-1 compact q0 (256-atom segments), waves 2-3 compact q1; per-query
//    2-wave prefix (2 barriers total). All 4 waves then pull 32-pair chunks
//    round-robin from the combined pool; two accumulator triples per wave.
//  - Hot loop byte-identical to R17: permuted-W1 X-build (quads 0-1 pure exp),
//    transposed K=32 MFMA + per-wave LDS exchange, fused L4+accumulation.
//  - LDS ~32.5KB -> 4 blocks/CU cap. fp16 in / fp32 accum; absmax 0.015625.

typedef _Float16 f16x8 __attribute__((ext_vector_type(8)));
typedef _Float16 f16x4 __attribute__((ext_vector_type(4)));
typedef _Float16 f16x2 __attribute__((ext_vector_type(2)));
typedef float    f32x4 __attribute__((ext_vector_type(4)));

#define CAP 352   // max in-range atoms/query (geometric max ~270)
#define XP2 72    // exchange row pitch in f16 (144B rows; b64/b128 aligned)
#define NT  2     // tiles (16 pairs) interleaved per chunk

// ---- repack: weights -> MFMA fragment order in d_ws (R17 permutation) ----
// W1aug K: k 0..15 = RBF centers (W1 rows 2..17), k16 = b1, k17 = W1 row0 (f0),
// k18 = W1 row1 (f1), k19.. = 0.
__global__ __launch_bounds__(64) void repack_kernel(
    const float* __restrict__ W1, const float* __restrict__ b1,
    const float* __restrict__ W2, const float* __restrict__ b2,
    const float* __restrict__ W3, const float* __restrict__ b3,
    const float* __restrict__ W4, char* __restrict__ ws)
{
    const int b = blockIdx.x, l = threadIdx.x;
    const int col = l & 15, quad = l >> 4;
    if (b < 16) {
        f16x8 v;
        #pragma unroll
        for (int j = 0; j < 8; ++j) {
            const int k = quad*8 + j;
            float x;
            if (b < 4) {
                const int mt = b;
                if (k < 16)       x = W1[(2 + k)*64 + mt*16 + col];
                else if (k == 16) x = b1[mt*16 + col];
                else if (k == 17) x = W1[0*64 + mt*16 + col];
                else if (k == 18) x = W1[1*64 + mt*16 + col];
                else              x = 0.0f;
            } else if (b < 12) {
                const int kc = (b-4) >> 2, mt = (b-4) & 3;
                x = W2[(kc*32 + k)*64 + mt*16 + col];
            } else {
                const int kc = (b-12) >> 1, mt = (b-12) & 1;
                x = W3[(kc*32 + k)*32 + mt*16 + col];
            }
            v[j] = (_Float16)x;
        }
        *(f16x8*)(ws + (b*64 + l)*16) = v;
    } else {
        const int d = b - 16;
        float o[4];
        #pragma unroll
        for (int rr = 0; rr < 4; ++rr) {
            const int idx = quad*4 + rr;
            if (d < 4)      o[rr] = b2[d*16 + idx];
            else if (d < 6) o[rr] = b3[(d-4)*16 + idx];
            else            o[rr] = W4[(d-6)*16 + idx];
        }
        *(float4*)(ws + 16384 + (d*64 + l)*16) = make_float4(o[0],o[1],o[2],o[3]);
    }
}

__global__ __launch_bounds__(256, 1) void aqfn_kernel(
    const float* __restrict__ atom_pos,   // (512,3)
    const float* __restrict__ atom_feat,  // (512,2)
    const float* __restrict__ query_pos,  // (4096,3)
    const float* __restrict__ b4,         // (1)
    const float* __restrict__ W5, const float* __restrict__ b5,  // (3,64),(64)
    const float* __restrict__ W6, const float* __restrict__ b6,  // (64,3),(3)
    const char*  __restrict__ ws,         // repacked weights
    float* __restrict__ out)              // (4096,3)
{
    __shared__ __align__(16) float4   rbuf[2][CAP];         // per-query lists
    __shared__ __align__(16) f16x2    fbuf[2][CAP];
    __shared__ __align__(16) _Float16 exch[4][NT][16*XP2];  // per-wave exchange
    __shared__ float wred[4][2][3];
    __shared__ int   wcnt[4];

    const int tid  = threadIdx.x;
    const int wave = __builtin_amdgcn_readfirstlane(tid >> 6);
    const int lane = tid & 63;
    const int col  = lane & 15;
    const int quad = lane >> 4;
    const int qsel = wave >> 1;          // query this wave compacts (0/1)
    const int seg  = wave & 1;           // 256-atom segment within it

    // ---- fragment preload: 24 coalesced dwordx4 loads (per wave) ----
    const f16x8*  wsf = (const f16x8*)ws;
    const float4* wsb = (const float4*)(ws + 16384);
    f16x8 w1f[4], w2f[2][4], w3f[2][2];
    #pragma unroll
    for (int mt = 0; mt < 4; ++mt) w1f[mt] = wsf[mt*64 + lane];
    #pragma unroll
    for (int kc = 0; kc < 2; ++kc)
        #pragma unroll
        for (int mt = 0; mt < 4; ++mt) w2f[kc][mt] = wsf[(4 + kc*4 + mt)*64 + lane];
    #pragma unroll
    for (int kc = 0; kc < 2; ++kc)
        #pragma unroll
        for (int mt = 0; mt < 2; ++mt) w3f[kc][mt] = wsf[(12 + kc*2 + mt)*64 + lane];
    float4 b2v[4], b3v[2], w4v[2];
    #pragma unroll
    for (int mt = 0; mt < 4; ++mt) b2v[mt] = wsb[mt*64 + lane];
    #pragma unroll
    for (int mt = 0; mt < 2; ++mt) { b3v[mt] = wsb[(4+mt)*64 + lane];
                                     w4v[mt] = wsb[(6+mt)*64 + lane]; }
    const float b4v = b4[0];

    // per-lane RBF center base for k = quad*8 + j
    const float cbase = 0.4f * (float)(quad*8);
    const bool  lowq  = (quad < 2);
    const bool  isq2  = (quad == 2);

    // ---- pass 1: ballots over segment [seg*256, +256) of query qsel ----
    const int qg = blockIdx.x*2 + qsel;
    const float qx = query_pos[qg*3+0];
    const float qy = query_pos[qg*3+1];
    const float qz = query_pos[qg*3+2];

    float rxv[4], ryv[4], rzv[4], dv[4], f0v[4], f1v[4];
    unsigned long long msk[4];
    int mycnt = 0;
    #pragma unroll
    for (int it = 0; it < 4; ++it) {
        const int a = seg*256 + it*64 + lane;
        const float rx = qx - atom_pos[a*3+0];
        const float ry = qy - atom_pos[a*3+1];
        const float rz = qz - atom_pos[a*3+2];
        const float ex = __fadd_rn(rx, 1e-12f);
        const float ey = __fadd_rn(ry, 1e-12f);
        const float ez = __fadd_rn(rz, 1e-12f);
        const float dd = __fadd_rn(__fadd_rn(__fmul_rn(ex,ex), __fmul_rn(ey,ey)),
                                   __fmul_rn(ez,ez));
        const float dist = sqrtf(dd);
        rxv[it] = rx; ryv[it] = ry; rzv[it] = rz; dv[it] = dist;
        f0v[it] = atom_feat[a*2+0]; f1v[it] = atom_feat[a*2+1];
        msk[it] = __ballot(dist <= 6.0f);
        mycnt  += (int)__popcll(msk[it]);
    }
    if (lane == 0) wcnt[wave] = mycnt;
    __syncthreads();

    // per-query prefix (2 contributing waves each) + both counts
    int cnt0 = wcnt[0] + wcnt[1];
    int cnt1 = wcnt[2] + wcnt[3];
    int base = (seg == 1) ? wcnt[qsel*2] : 0;
    if (cnt0 > CAP) cnt0 = CAP;
    if (cnt1 > CAP) cnt1 = CAP;

    // ---- pass 2: prefix-offset writes into this query's list ----
    {
        int off0 = base;
        #pragma unroll
        for (int it = 0; it < 4; ++it) {
            const bool in = (msk[it] >> lane) & 1ull;
            const int  p  = off0 + (int)__popcll(msk[it] & ((1ull << lane) - 1ull));
            if (in && p < CAP) {
                rbuf[qsel][p] = make_float4(rxv[it], ryv[it], rzv[it], dv[it]);
                fbuf[qsel][p] = f16x2{(_Float16)f0v[it], (_Float16)f1v[it]};
            }
            off0 += (int)__popcll(msk[it]);
        }
    }
    __syncthreads();

    // ---- MLP over combined pool: 32-pair chunks round-robin across 4 waves ----
    float acc[2][3] = {{0,0,0},{0,0,0}};
    const int nch0 = (cnt0 + (NT*16 - 1)) / (NT*16);
    const int nch1 = (cnt1 + (NT*16 - 1)) / (NT*16);
    const int ntot = nch0 + nch1;

    #pragma unroll 1
    for (int g = wave; g < ntot; g += 4) {
        const int cq    = (g < nch0) ? 0 : 1;            // wave-uniform
        const int lc    = (g < nch0) ? g : (g - nch0);
        const int count = (cq == 0) ? cnt0 : cnt1;
        const float4* __restrict__ rb = &rbuf[cq][0];
        const f16x2*  __restrict__ fb = &fbuf[cq][0];
        const int row0 = lc * (NT*16);

        float4 rv[NT]; f16x2 ffv[NT];
        #pragma unroll
        for (int u = 0; u < NT; ++u) {
            int pr = row0 + u*16 + col;
            if (pr >= count) pr = count - 1;
            rv[u]  = rb[pr];
            ffv[u] = fb[pr];
        }

        // X B-frags (permuted W1aug): x = [rbf(16) | 1 | f0 | f1 | 0...]
        f16x8 xa[NT];
        #pragma unroll
        for (int u = 0; u < NT; ++u) {
            const float dist = rv[u].w;
            const _Float16 f0h = ffv[u][0], f1h = ffv[u][1];
            const _Float16 z   = (_Float16)0.0f;
            #pragma unroll
            for (int j = 0; j < 8; ++j) {
                const float tt = dist - (cbase + 0.4f * (float)j);
                const _Float16 e = (_Float16)__expf(-10.0f * tt * tt);
                _Float16 sp;
                if      (j == 0) sp = isq2 ? (_Float16)1.0f : z;
                else if (j == 1) sp = isq2 ? f0h : z;
                else if (j == 2) sp = isq2 ? f1h : z;
                else             sp = z;
                xa[u][j] = lowq ? e : sp;
            }
        }

        // ---- L1 transposed ----
        #pragma unroll
        for (int u = 0; u < NT; ++u)
            #pragma unroll
            for (int mt = 0; mt < 4; ++mt) {
                f32x4 c = {0.f, 0.f, 0.f, 0.f};
                c = __builtin_amdgcn_mfma_f32_16x16x32_f16(w1f[mt], xa[u], c, 0, 0, 0);
                f16x4 pk = {(_Float16)fmaxf(c[0],0.f), (_Float16)fmaxf(c[1],0.f),
                            (_Float16)fmaxf(c[2],0.f), (_Float16)fmaxf(c[3],0.f)};
                *(f16x4*)&exch[wave][u][col*XP2 + mt*16 + quad*4] = pk;
            }
        f16x8 a2[NT][2];
        #pragma unroll
        for (int u = 0; u < NT; ++u)
            #pragma unroll
            for (int kc = 0; kc < 2; ++kc)
                a2[u][kc] = *(const f16x8*)&exch[wave][u][col*XP2 + kc*32 + quad*8];

        // ---- L2 transposed ----
        #pragma unroll
        for (int u = 0; u < NT; ++u)
            #pragma unroll
            for (int mt = 0; mt < 4; ++mt) {
                f32x4 c = {b2v[mt].x, b2v[mt].y, b2v[mt].z, b2v[mt].w};
                c = __builtin_amdgcn_mfma_f32_16x16x32_f16(w2f[0][mt], a2[u][0], c, 0, 0, 0);
                c = __builtin_amdgcn_mfma_f32_16x16x32_f16(w2f[1][mt], a2[u][1], c, 0, 0, 0);
                f16x4 pk = {(_Float16)fmaxf(c[0],0.f), (_Float16)fmaxf(c[1],0.f),
                            (_Float16)fmaxf(c[2],0.f), (_Float16)fmaxf(c[3],0.f)};
                *(f16x4*)&exch[wave][u][col*XP2 + mt*16 + quad*4] = pk;
            }
        f16x8 a3[NT][2];
        #pragma unroll
        for (int u = 0; u < NT; ++u)
            #pragma unroll
            for (int kc = 0; kc < 2; ++kc)
                a3[u][kc] = *(const f16x8*)&exch[wave][u][col*XP2 + kc*32 + quad*8];

        // ---- L3 transposed + L4 partial + quad-reduce + fused accumulation ----
        #pragma unroll
        for (int u = 0; u < NT; ++u) {
            float s = 0.f;
            #pragma unroll
            for (int mt = 0; mt < 2; ++mt) {
                f32x4 c = {b3v[mt].x, b3v[mt].y, b3v[mt].z, b3v[mt].w};
                c = __builtin_amdgcn_mfma_f32_16x16x32_f16(w3f[0][mt], a3[u][0], c, 0, 0, 0);
                c = __builtin_amdgcn_mfma_f32_16x16x32_f16(w3f[1][mt], a3[u][1], c, 0, 0, 0);
                const float* wv = &w4v[mt].x;
                #pragma unroll
                for (int rr = 0; rr < 4; ++rr)
                    s = fmaf(fmaxf(c[rr], 0.f), wv[rr], s);
            }
            s += __shfl_xor(s, 16);
            s += __shfl_xor(s, 32);
            s += b4v;
            const int  p2  = row0 + u*16 + col;
            const bool vld = (p2 < count);
            const float inv = __builtin_amdgcn_rcpf(rv[u].w + 1e-12f);
            const float wm  = vld ? (s * inv) : 0.f;
            if (cq == 0) {
                acc[0][0] = fmaf(wm, rv[u].x, acc[0][0]);
                acc[0][1] = fmaf(wm, rv[u].y, acc[0][1]);
                acc[0][2] = fmaf(wm, rv[u].z, acc[0][2]);
            } else {
                acc[1][0] = fmaf(wm, rv[u].x, acc[1][0]);
                acc[1][1] = fmaf(wm, rv[u].y, acc[1][1]);
                acc[1][2] = fmaf(wm, rv[u].z, acc[1][2]);
            }
        }
    }

    // ---- butterflies (x0.25: each pair counted by 4 quads) ----
    #pragma unroll
    for (int cq = 0; cq < 2; ++cq)
        #pragma unroll
        for (int d = 0; d < 3; ++d) {
            float v = acc[cq][d];
            #pragma unroll
            for (int off = 1; off < 64; off <<= 1) v += __shfl_xor(v, off);
            if (lane == 0) wred[wave][cq][d] = v * 0.25f;
        }
    __syncthreads();

    // ---- heads in parallel: wave 0 -> q0, wave 1 -> q1 ----
    if (wave < 2) {
        const int cq = wave;
        const float v0 = wred[0][cq][0] + wred[1][cq][0] + wred[2][cq][0] + wred[3][cq][0];
        const float v1 = wred[0][cq][1] + wred[1][cq][1] + wred[2][cq][1] + wred[3][cq][1];
        const float v2 = wred[0][cq][2] + wred[1][cq][2] + wred[2][cq][2] + wred[3][cq][2];
        float th = fmaf(v0, W5[lane],
                   fmaf(v1, W5[64+lane],
                   fmaf(v2, W5[128+lane], b5[lane])));
        th = fmaxf(th, 0.f);
        float o0 = th * W6[lane*3+0];
        float o1 = th * W6[lane*3+1];
        float o2 = th * W6[lane*3+2];
        #pragma unroll
        for (int off = 1; off < 64; off <<= 1) {
            o0 += __shfl_xor(o0, off);
            o1 += __shfl_xor(o1, off);
            o2 += __shfl_xor(o2, off);
        }
        if (lane == 0) {
            const int qo = blockIdx.x*2 + cq;
            out[qo*3+0] = o0 + b6[0];
            out[qo*3+1] = o1 + b6[1];
            out[qo*3+2] = o2 + b6[2];
        }
    }
}

extern "C" void kernel_launch(void* const* d_in, const int* in_sizes, int n_in,
                              void* d_out, int out_size, void* d_ws, size_t ws_size,
                              hipStream_t stream) {
    const float* atom_pos  = (const float*)d_in[0];
    const float* atom_feat = (const float*)d_in[1];
    const float* query_pos = (const float*)d_in[2];
    const float* W1 = (const float*)d_in[3];  const float* b1 = (const float*)d_in[4];
    const float* W2 = (const float*)d_in[5];  const float* b2 = (const float*)d_in[6];
    const float* W3 = (const float*)d_in[7];  const float* b3 = (const float*)d_in[8];
    const float* W4 = (const float*)d_in[9];  const float* b4 = (const float*)d_in[10];
    const float* W5 = (const float*)d_in[11]; const float* b5 = (const float*)d_in[12];
    const float* W6 = (const float*)d_in[13]; const float* b6 = (const float*)d_in[14];
    float* out = (float*)d_out;
    char*  ws  = (char*)d_ws;   // 16KB frags + 8KB biases

    hipLaunchKernelGGL(repack_kernel, dim3(24), dim3(64), 0, stream,
                       W1, b1, W2, b2, W3, b3, W4, ws);
    hipLaunchKernelGGL(aqfn_kernel, dim3(2048), dim3(256), 0, stream,
                       atom_pos, atom_feat, query_pos, b4, W5, b5, W6, b6,
                       (const char*)ws, out);
}